// Round 4
// baseline (163.905 us; speedup 1.0000x reference)
//
#include <hip/hip_runtime.h>

#define WAVE 64

typedef float v4f __attribute__((ext_vector_type(4)));

// ---------------------------------------------------------------------------
// Kernel 0: zero the [B][5] accumulator (sums.xyzw + count). Poison-immune:
// every word rewritten each launch.
// ---------------------------------------------------------------------------
__global__ void zero_acc_kernel(float* __restrict__ acc, int n) {
    const int i = blockIdx.x * blockDim.x + threadIdx.x;
    if (i < n) acc[i] = 0.0f;
}

// ---------------------------------------------------------------------------
// Kernel 1: node-centric streaming pass. Each wave processes contiguous
// 64-node chunks (grid-stride): one perfectly-coalesced float4 load of x and
// one int load of batch per lane — the same pure-streaming pattern the
// harness fill kernels run at 6.6 TB/s. batch is sorted, so each chunk is a
// few non-decreasing runs; a wave-level segmented inclusive scan (6 shuffle
// steps, guarded by run-equality) leaves each run's total in its LAST lane,
// which atomicAdds {sum.xyzw, count} into acc[seg]. ~1.2 run-ends per chunk
// -> ~470K atomics total onto 82K L2-resident words: negligible.
// This replaces the R3 two-pass structure (separate 20 MB batch scan +
// per-segment-wave x pass whose ~4.9 KB/wave loops under-utilize BW).
// ---------------------------------------------------------------------------
__global__ void __launch_bounds__(256)
partial_sums_kernel(const v4f* __restrict__ x,
                    const int* __restrict__ batch,
                    float* __restrict__ acc,   // [B][5]
                    int N) {
    const int nwaves = (gridDim.x * blockDim.x) >> 6;
    const int gwave  = (blockIdx.x * blockDim.x + threadIdx.x) >> 6;
    const int lane   = threadIdx.x & (WAVE - 1);
    const int nchunks = (N + WAVE - 1) >> 6;

    for (int c = gwave; c < nchunks; c += nwaves) {
        const int i = (c << 6) + lane;
        v4f v = (v4f)(0.0f);
        int seg = -1;
        if (i < N) {
            v   = __builtin_nontemporal_load(&x[i]);
            seg = __builtin_nontemporal_load(&batch[i]);
        }

        // Segmented inclusive scan across the wave (runs keyed by seg).
        #pragma unroll
        for (int off = 1; off < WAVE; off <<= 1) {
            float ox = __shfl_up(v.x, off);
            float oy = __shfl_up(v.y, off);
            float oz = __shfl_up(v.z, off);
            float ow = __shfl_up(v.w, off);
            int   os = __shfl_up(seg, off);
            if (lane >= off && os == seg) {
                v.x += ox; v.y += oy; v.z += oz; v.w += ow;
            }
        }

        const int nseg = __shfl_down(seg, 1);
        const bool last = (lane == WAVE - 1) || (nseg != seg);

        const int pseg = __shfl_up(seg, 1);
        const bool head = (lane == 0) || (pseg != seg);
        const unsigned long long hmask = __ballot(head);

        if (last && seg >= 0) {
            // First lane of my run = highest set head-bit at or below me.
            // (2ULL<<63)-1 wraps to all-ones, so no lane-63 special case.
            const unsigned long long below = hmask & ((2ULL << lane) - 1ULL);
            const int startl = 63 - __clzll(below);
            const float cnt = (float)(lane - startl + 1);
            float* a = acc + (long long)seg * 5;
            atomicAdd(a + 0, v.x);
            atomicAdd(a + 1, v.y);
            atomicAdd(a + 2, v.z);
            atomicAdd(a + 3, v.w);
            atomicAdd(a + 4, cnt);
        }
    }
}

// ---------------------------------------------------------------------------
// Kernel 2: one thread per graph. mean = sum/count (0 if empty), then the
// fused MLP: h=[u,mean] -> leaky_relu(h@W1+b1) -> @W2+b2. acc is L2-resident.
// ---------------------------------------------------------------------------
__global__ void __launch_bounds__(256)
mlp_kernel(const float* __restrict__ acc,   // [B][5]
           const float* __restrict__ u,
           const float* __restrict__ W1,    // [5,5] row-major
           const float* __restrict__ b1,    // [5]
           const float* __restrict__ W2,    // [5]
           const float* __restrict__ b2,    // [1]
           float* __restrict__ out, int B) {
    const int s = blockIdx.x * blockDim.x + threadIdx.x;
    if (s >= B) return;

    const float* a = acc + (long long)s * 5;
    const float cnt = a[4];
    const float inv = (cnt > 0.0f) ? (1.0f / cnt) : 0.0f;

    float h[5];
    h[0] = u[s];
    h[1] = a[0] * inv;
    h[2] = a[1] * inv;
    h[3] = a[2] * inv;
    h[4] = a[3] * inv;

    float o = b2[0];
    #pragma unroll
    for (int j = 0; j < 5; ++j) {
        float t = b1[j];
        #pragma unroll
        for (int i2 = 0; i2 < 5; ++i2) t += h[i2] * W1[i2 * 5 + j];
        t = (t > 0.0f) ? t : 0.1f * t;   // leaky_relu, slope 0.1
        o += t * W2[j];
    }
    out[s] = o;
}

extern "C" void kernel_launch(void* const* d_in, const int* in_sizes, int n_in,
                              void* d_out, int out_size, void* d_ws, size_t ws_size,
                              hipStream_t stream) {
    const float* x     = (const float*)d_in[0];  // [N,4]
    const int*   batch = (const int*)  d_in[1];  // [N]
    const float* u     = (const float*)d_in[2];  // [B,1]
    const float* W1    = (const float*)d_in[3];  // [5,5]
    const float* b1    = (const float*)d_in[4];  // [5]
    const float* W2    = (const float*)d_in[5];  // [5,1]
    const float* b2    = (const float*)d_in[6];  // [1]
    float* out = (float*)d_out;

    const int N = in_sizes[0] / 4;
    const int B = out_size;                      // output is [B,1]

    float* acc = (float*)d_ws;                   // [B][5] floats
    const int accN = B * 5;

    zero_acc_kernel<<<(accN + 255) / 256, 256, 0, stream>>>(acc, accN);

    // 2048 blocks x 256 thr = 8192 waves; ~9.5 chunks/wave, grid-stride.
    partial_sums_kernel<<<2048, 256, 0, stream>>>(
        (const v4f*)x, batch, acc, N);

    mlp_kernel<<<(B + 255) / 256, 256, 0, stream>>>(
        acc, u, W1, b1, W2, b2, out, B);
}

// Round 5
// 141.886 us; speedup vs baseline: 1.1552x; 1.1552x over previous
//
#include <hip/hip_runtime.h>

#define WAVE 64

typedef float v4f __attribute__((ext_vector_type(4)));
typedef int   v4i __attribute__((ext_vector_type(4)));

// ---------------------------------------------------------------------------
// Kernel A: segment start offsets from the sorted batch index, vectorized.
// seg_start[s] = min{ i : batch[i] >= s } for s in [0,B]; seg_start[B] = N.
// One int4 per thread; the quad's predecessor element comes from the
// neighbor lane via __shfl_up (only lane 0 of each wave loads it).
// Every s in [0,B] is written exactly once -> no init needed (poison-immune).
// Plain (allocating) loads: batch may then be L3-resident for later
// iterations (R4 evidence: FETCH_SIZE ~ half of bytes-read despite poison
// fill -> Infinity Cache retains inputs across iterations).
// ---------------------------------------------------------------------------
__global__ void find_starts4_kernel(const int* __restrict__ batch,
                                    int* __restrict__ seg_start,
                                    int N, int B) {
    const int tid  = blockIdx.x * blockDim.x + threadIdx.x;
    const int lane = threadIdx.x & (WAVE - 1);
    const long long i0 = (long long)tid * 4;
    const bool in   = (i0 < N);
    const bool full = (i0 + 3 < N);

    v4i q = (v4i)(0);
    if (full) q = ((const v4i*)batch)[tid];

    // Predecessor of this quad = last element of the previous thread's quad.
    // All threads participate in the shuffle before any early exit.
    int prevw = __shfl_up(q.w, 1);

    if (!in) return;

    int prev;
    if (lane == 0) prev = (i0 == 0) ? -1 : batch[i0 - 1];
    else           prev = prevw;      // predecessor quad is always full here

    if (full) {
        int e[4] = {q.x, q.y, q.z, q.w};
        #pragma unroll
        for (int k = 0; k < 4; ++k) {
            int cur = e[k];
            for (int s = prev + 1; s <= cur; ++s) seg_start[s] = (int)(i0 + k);
            prev = cur;
        }
    } else {
        for (long long j = i0; j < N; ++j) {
            int cur = batch[j];
            for (int s = prev + 1; s <= cur; ++s) seg_start[s] = (int)j;
            prev = cur;
        }
    }

    if (i0 + 4 >= N) {  // owner of the final quad writes the tail sentinels
        for (int s = prev + 1; s <= B; ++s) seg_start[s] = N;
    }
}

// ---------------------------------------------------------------------------
// Kernel B: one wave per segment. Coalesced float4 accumulation, 4x unrolled
// (4 loads in flight), wave tree-reduction, then lane 0 computes the fused
// MLP: h=[u,mean] -> leaky_relu(h@W1+b1) -> @W2+b2.
// Plain loads (NOT nontemporal): single-variable experiment vs R3 — allow x
// to allocate into the 256 MB L3 so iterations after the first get L3-BW
// reads (the harness poison fill does not appear to evict via L3).
// ---------------------------------------------------------------------------
__global__ void __launch_bounds__(256)
seg_mean_mlp_kernel(const v4f* __restrict__ x,
                    const int* __restrict__ seg_start,
                    const float* __restrict__ u,
                    const float* __restrict__ W1,   // [5,5] row-major
                    const float* __restrict__ b1,   // [5]
                    const float* __restrict__ W2,   // [5]
                    const float* __restrict__ b2,   // [1]
                    float* __restrict__ out, int B) {
    const int wid  = (blockIdx.x * blockDim.x + threadIdx.x) >> 6;
    const int lane = threadIdx.x & (WAVE - 1);
    if (wid >= B) return;

    const int start = seg_start[wid];
    const int end   = seg_start[wid + 1];

    v4f a0 = (v4f)(0.f);
    v4f a1 = (v4f)(0.f);
    v4f a2 = (v4f)(0.f);
    v4f a3 = (v4f)(0.f);

    int i = start + lane;
    for (; i + 3 * WAVE < end; i += 4 * WAVE) {
        v4f v0 = x[i];
        v4f v1 = x[i + WAVE];
        v4f v2 = x[i + 2 * WAVE];
        v4f v3 = x[i + 3 * WAVE];
        a0 += v0; a1 += v1; a2 += v2; a3 += v3;
    }
    for (; i < end; i += WAVE) {
        a0 += x[i];
    }

    a0 += a1; a2 += a3; a0 += a2;

    float sx = a0.x, sy = a0.y, sz = a0.z, sw = a0.w;
    #pragma unroll
    for (int off = 32; off > 0; off >>= 1) {
        sx += __shfl_down(sx, off);
        sy += __shfl_down(sy, off);
        sz += __shfl_down(sz, off);
        sw += __shfl_down(sw, off);
    }

    if (lane == 0) {
        const int cnt = end - start;
        const float inv = (cnt > 0) ? (1.0f / (float)cnt) : 0.0f;

        float h[5];
        h[0] = u[wid];
        h[1] = sx * inv;
        h[2] = sy * inv;
        h[3] = sz * inv;
        h[4] = sw * inv;

        float o = b2[0];
        #pragma unroll
        for (int j = 0; j < 5; ++j) {
            float s = b1[j];
            #pragma unroll
            for (int i2 = 0; i2 < 5; ++i2) s += h[i2] * W1[i2 * 5 + j];
            s = (s > 0.0f) ? s : 0.1f * s;   // leaky_relu, slope 0.1
            o += s * W2[j];
        }
        out[wid] = o;
    }
}

extern "C" void kernel_launch(void* const* d_in, const int* in_sizes, int n_in,
                              void* d_out, int out_size, void* d_ws, size_t ws_size,
                              hipStream_t stream) {
    const float* x     = (const float*)d_in[0];  // [N,4]
    const int*   batch = (const int*)  d_in[1];  // [N]
    const float* u     = (const float*)d_in[2];  // [B,1]
    const float* W1    = (const float*)d_in[3];  // [5,5]
    const float* b1    = (const float*)d_in[4];  // [5]
    const float* W2    = (const float*)d_in[5];  // [5,1]
    const float* b2    = (const float*)d_in[6];  // [1]
    float* out = (float*)d_out;

    const int N = in_sizes[0] / 4;
    const int B = out_size;                      // output is [B,1]

    int* seg_start = (int*)d_ws;                 // [B+1] ints, fully rewritten

    const int quads = (N + 3) / 4;
    find_starts4_kernel<<<(quads + 255) / 256, 256, 0, stream>>>(batch, seg_start, N, B);

    const int threads = 256;
    const int blocks  = (int)(((long long)B * WAVE + threads - 1) / threads);
    seg_mean_mlp_kernel<<<blocks, threads, 0, stream>>>(
        (const v4f*)x, seg_start, u, W1, b1, W2, b2, out, B);
}